// Round 8
// baseline (358.650 us; speedup 1.0000x reference)
//
#include <hip/hip_runtime.h>
#include <hip/hip_bf16.h>

#define EMB 1024
#define THREE_EMB 3072
#define T_SEQ 2048
#define NB 4
#define NH 16
#define HD 64
#define MROWS 8192  // NB * T_SEQ
#define NBH 64      // NB * NH

// 0.125 * log2(e): fold score scale AND exp->exp2 conversion into Q
#define QSCALE 0.18033688011112042f

typedef _Float16 half8 __attribute__((ext_vector_type(8)));
typedef _Float16 half4v __attribute__((ext_vector_type(4)));
typedef float f32x4v __attribute__((ext_vector_type(4)));

static __device__ __forceinline__ f32x4v mfma16(half8 a, half8 b, f32x4v c) {
  return __builtin_amdgcn_mfma_f32_16x16x32_f16(a, b, c, 0, 0, 0);
}

// async global->LDS, 16B per lane. LDS dest = wave-uniform base + lane*16.
static __device__ __forceinline__ void gload16(const void* g, void* l) {
  __builtin_amdgcn_global_load_lds(
      (const __attribute__((address_space(1))) void*)g,
      (__attribute__((address_space(3))) void*)l, 16, 0, 0);
}

// ---------------------------------------------------------------------------
// Pre-pass: split x (fp32) into f16 hi/lo, 8 elems/thread.
// ---------------------------------------------------------------------------
__global__ __launch_bounds__(256) void split_x(const float* __restrict__ X,
                                               _Float16* __restrict__ H,
                                               _Float16* __restrict__ L) {
  const size_t i = ((size_t)blockIdx.x * 256 + threadIdx.x) * 8;
  const float4 a = *(const float4*)&X[i];
  const float4 b = *(const float4*)&X[i + 4];
  const float va[8] = {a.x, a.y, a.z, a.w, b.x, b.y, b.z, b.w};
  half8 h, l;
#pragma unroll
  for (int j = 0; j < 8; ++j) {
    const _Float16 hh = (_Float16)va[j];
    h[j] = hh;
    l[j] = (_Float16)(va[j] - (float)hh);
  }
  *(half8*)&H[i] = h;
  *(half8*)&L[i] = l;
}

// ---------------------------------------------------------------------------
// Pre-pass: W [1024][N] fp32 -> Wt hi/lo [N][1024] f16 (32x32 LDS transpose).
// ---------------------------------------------------------------------------
__global__ __launch_bounds__(256) void tsplit_w(const float* __restrict__ W,
                                                _Float16* __restrict__ Th,
                                                _Float16* __restrict__ Tl,
                                                int N) {
  __shared__ float tile[32][33];
  const int tid = threadIdx.x;
  const int k0 = blockIdx.x * 32;
  const int n0 = blockIdx.y * 32;
  const int c = tid & 31;
  const int r4 = (tid >> 5) * 4;
#pragma unroll
  for (int rr = 0; rr < 4; ++rr)
    tile[r4 + rr][c] = W[(size_t)(k0 + r4 + rr) * N + n0 + c];
  __syncthreads();
#pragma unroll
  for (int rr = 0; rr < 4; ++rr) {
    const float v = tile[c][r4 + rr];
    const _Float16 hi = (_Float16)v;
    Th[(size_t)(n0 + r4 + rr) * EMB + k0 + c] = hi;
    Tl[(size_t)(n0 + r4 + rr) * EMB + k0 + c] = (_Float16)(v - (float)hi);
  }
}

// ---------------------------------------------------------------------------
// MFMA split-f16 GEMM: C = A @ B^T + bias (3-term f16 split, fp32 accum).
// 128x128 tile, 4 waves (2x2) of 64x64. PIPELINED: BK=32, two LDS buffers
// (2 x 32KB), ONE barrier per phase; stage(t+1) issued after barrier(t),
// waited at barrier(t+1) -> staging latency hidden under the phase compute.
// LDS rows = 4 chunks of 16B, slot XOR-swizzled by (row>>1)&3 (2-way = free;
// row&3 would be 4-way since r&1 is determined by r&3). Inverse swizzle on
// the global source address (within one 64B line -> coalescing unchanged).
// MODE 0: QKV epilogue (Q hi/lo scaled, K single f16, V transposed f16).
// MODE 1: fp32 out + bias.
// ---------------------------------------------------------------------------
template <int MODE>
__global__ __launch_bounds__(256) void mfma_gemm(
    const _Float16* __restrict__ Ah, const _Float16* __restrict__ Al,
    const _Float16* __restrict__ Bh, const _Float16* __restrict__ Bl,
    const float* __restrict__ bias, float* __restrict__ OutF,
    _Float16* __restrict__ Qhi, _Float16* __restrict__ Qlo,
    _Float16* __restrict__ Kh, _Float16* __restrict__ Vt) {
  __shared__ __align__(16) _Float16 S[2][4][128 * 32];  // [buf][stream]

  const int tid = threadIdx.x;
  const int w = tid >> 6;
  const int lane = tid & 63;
  const int l15 = lane & 15;
  const int lhi = lane >> 4;
  const int wm = w >> 1, wn = w & 1;
  const int m0 = blockIdx.x * 128;
  const int n0 = blockIdx.y * 128;

  // staging: wave w owns stream w. Per gload16 i: rows i*16+(lane>>2),
  // dest slot lane&3; source chunk = (lane&3) ^ ((row>>1)&3), row=lane>>2.
  const int srow = lane >> 2;
  const int schunk8 = ((lane & 3) ^ ((lane >> 3) & 3)) * 8;
  const _Float16* gs;
  if (w == 0) gs = Ah + (size_t)m0 * EMB;
  else if (w == 1) gs = Al + (size_t)m0 * EMB;
  else if (w == 2) gs = Bh + (size_t)n0 * EMB;
  else gs = Bl + (size_t)n0 * EMB;
  const _Float16* gl = gs + (size_t)srow * EMB + schunk8;

#define GSTAGE(buf, k0_)                                                    \
  {                                                                         \
    _Pragma("unroll") for (int i = 0; i < 8; ++i)                           \
        gload16(gl + (k0_) + (size_t)i * 16 * EMB, &S[buf][w][i * 512]);    \
  }

  f32x4v acc[4][4];
#pragma unroll
  for (int mi = 0; mi < 4; ++mi)
#pragma unroll
    for (int ni = 0; ni < 4; ++ni) acc[mi][ni] = (f32x4v){0.f, 0.f, 0.f, 0.f};

  // read side: frag row = base + mi*16 + l15, chunk lhi,
  // slot = lhi ^ ((row>>1)&3) = lhi ^ ((l15>>1)&3)  (base multiple of 16)
  const int slot8 = (lhi ^ ((l15 >> 1) & 3)) * 8;
  const int aoff = (wm * 64 + l15) * 32 + slot8;
  const int boff = (wn * 64 + l15) * 32 + slot8;

#define GPHASE(buf, k0_, do_stage, sbuf, sk)                                \
  {                                                                         \
    asm volatile("s_waitcnt vmcnt(0)" ::: "memory");                        \
    __builtin_amdgcn_s_barrier();                                           \
    __builtin_amdgcn_sched_barrier(0);                                      \
    if (do_stage) GSTAGE(sbuf, sk);                                         \
    __builtin_amdgcn_sched_barrier(0);                                      \
    half8 am[2][4], bn[2][4];                                               \
    _Pragma("unroll") for (int mi = 0; mi < 4; ++mi) {                      \
      am[0][mi] = *(const half8*)&S[buf][0][aoff + mi * 512];               \
      am[1][mi] = *(const half8*)&S[buf][1][aoff + mi * 512];               \
      bn[0][mi] = *(const half8*)&S[buf][2][boff + mi * 512];               \
      bn[1][mi] = *(const half8*)&S[buf][3][boff + mi * 512];               \
    }                                                                       \
    __builtin_amdgcn_s_setprio(1);                                          \
    _Pragma("unroll") for (int mi = 0; mi < 4; ++mi)                        \
        _Pragma("unroll") for (int ni = 0; ni < 4; ++ni) {                  \
      acc[mi][ni] = mfma16(am[0][mi], bn[0][ni], acc[mi][ni]);              \
      acc[mi][ni] = mfma16(am[1][mi], bn[0][ni], acc[mi][ni]);              \
      acc[mi][ni] = mfma16(am[0][mi], bn[1][ni], acc[mi][ni]);              \
    }                                                                       \
    __builtin_amdgcn_s_setprio(0);                                          \
  }

  GSTAGE(0, 0);
  for (int k0 = 0; k0 < EMB; k0 += 64) {
    GPHASE(0, k0, true, 1, k0 + 32);
    GPHASE(1, k0 + 32, (k0 + 64 < EMB), 0, k0 + 64);
  }
#undef GPHASE
#undef GSTAGE

  // ---- epilogue ----  C layout: row=(lane>>4)*4+reg, col=lane&15
  const int gmB = m0 + wm * 64 + lhi * 4;
  const int gnB = n0 + wn * 64 + l15;
  if (MODE == 1) {
#pragma unroll
    for (int mi = 0; mi < 4; ++mi)
#pragma unroll
      for (int ni = 0; ni < 4; ++ni) {
        const int gn = gnB + ni * 16;
        const float bi = bias[gn];
#pragma unroll
        for (int r = 0; r < 4; ++r) {
          const int gm = gmB + mi * 16 + r;
          OutF[(size_t)gm * EMB + gn] = acc[mi][ni][r] + bi;
        }
      }
  } else {
    const int which = n0 >> 10;  // 0:Q 1:K 2:V, uniform per block
#pragma unroll
    for (int mi = 0; mi < 4; ++mi) {
#pragma unroll
      for (int ni = 0; ni < 4; ++ni) {
        const int gn = gnB + ni * 16;
        const float bi = bias[gn];
        const int d = gn & 63;
        const int h = (gn >> 6) & 15;
        const int gm0 = gmB + mi * 16;
        const int b = gm0 >> 11;
        const int t0 = gm0 & 2047;
        const int bh = b * NH + h;
        if (which == 2) {
          half4v hv;
#pragma unroll
          for (int r = 0; r < 4; ++r) hv[r] = (_Float16)(acc[mi][ni][r] + bi);
          *(half4v*)&Vt[((size_t)bh * HD + d) * T_SEQ + t0] = hv;  // [bh][d][t]
        } else if (which == 1) {
#pragma unroll
          for (int r = 0; r < 4; ++r) {
            const float v = acc[mi][ni][r] + bi;
            Kh[((size_t)bh * T_SEQ + t0 + r) * HD + d] = (_Float16)v;
          }
        } else {
#pragma unroll
          for (int r = 0; r < 4; ++r) {
            const float v = (acc[mi][ni][r] + bi) * QSCALE;
            const _Float16 hi = (_Float16)v;
            const size_t idx = ((size_t)bh * T_SEQ + t0 + r) * HD + d;
            Qhi[idx] = hi;
            Qlo[idx] = (_Float16)(v - (float)hi);
          }
        }
      }
    }
  }
}

// ---------------------------------------------------------------------------
// MFMA flash attention, swapped-operand form (unchanged from round 7).
// ---------------------------------------------------------------------------
__global__ __launch_bounds__(256) void attn_kernel(
    const _Float16* __restrict__ Qhi, const _Float16* __restrict__ Qlo,
    const _Float16* __restrict__ Kh, const _Float16* __restrict__ Vt,
    _Float16* __restrict__ AOh, _Float16* __restrict__ AOl) {
  __shared__ __align__(16) _Float16 KhS[3][64 * 64];
  __shared__ __align__(16) _Float16 VtS[3][64 * 64];
  __shared__ __align__(16) _Float16 PS[4][16][80];

  const int tid = threadIdx.x;
  const int w = tid >> 6;
  const int lane = tid & 63;
  const int l15 = lane & 15;
  const int lhi = lane >> 4;
  const int sw = l15 & 7;
  const int swz = sw ^ ((l15 >> 3) << 2);  // PS slot swizzle (bank-complete)

  // XCD swizzle: xcd = bid&7 gets bh in [8*xcd, 8*xcd+8), all 16 q-blocks
  const int bid = blockIdx.x;
  const int idx = bid >> 3;
  const int bh = (bid & 7) * 8 + (idx & 7);
  const int qb = idx >> 3;
  const int q0 = qb * 128 + w * 32;
  const int b = bh >> 4;
  const int h = bh & 15;

  // Q B-fragments for 2 sub-tiles of 16 q (col=l15, k=d=lhi*8+j, m2*32)
  half8 qh[2][2], ql[2][2];
#pragma unroll
  for (int qf = 0; qf < 2; ++qf) {
    const size_t qbase =
        ((size_t)bh * T_SEQ + q0 + qf * 16 + l15) * HD + lhi * 8;
#pragma unroll
    for (int m2 = 0; m2 < 2; ++m2) {
      qh[qf][m2] = *(const half8*)&Qhi[qbase + m2 * 32];
      ql[qf][m2] = *(const half8*)&Qlo[qbase + m2 * 32];
    }
  }

  half8 ones;
#pragma unroll
  for (int j = 0; j < 8; ++j) ones[j] = (_Float16)1.0f;

  f32x4v O[2][4];  // O^T: [qf][c], elem r -> d = c*16+lhi*4+r, q = l15
  float m[2], l[2];
#pragma unroll
  for (int qf = 0; qf < 2; ++qf) {
    m[qf] = -1e30f;
    l[qf] = 0.f;
#pragma unroll
    for (int c = 0; c < 4; ++c) O[qf][c] = (f32x4v){0.f, 0.f, 0.f, 0.f};
  }

  // staging: wave w stages K/V rows w*16 + i*8 + (lane>>3), slot lane&7;
  // source chunk = slot ^ (row&7)  (row&7 == lane>>3 here)
  const int so = lane >> 3;
  const int schunk = ((lane & 7) ^ so) * 8;
  const size_t kgb = (size_t)bh * T_SEQ * HD;
  const size_t vgb = (size_t)bh * HD * T_SEQ;
  const int rb = w * 16;

#define STAGE(buf, kt_)                                              \
  {                                                                  \
    _Pragma("unroll") for (int i = 0; i < 2; ++i) {                  \
      const int row = rb + i * 8 + so;                               \
      gload16(Kh + kgb + (size_t)((kt_) + row) * HD + schunk,        \
              &KhS[(buf)][(rb + i * 8) * 64]);                       \
      gload16(Vt + vgb + (size_t)row * T_SEQ + (kt_) + schunk,       \
              &VtS[(buf)][(rb + i * 8) * 64]);                       \
    }                                                                \
  }

  STAGE(0, 0);
  STAGE(1, 64);
  int cur = 0;

  for (int kt = 0; kt < T_SEQ; kt += 64) {
    if (kt + 64 < T_SEQ) {
      asm volatile("s_waitcnt vmcnt(4)" ::: "memory");
    } else {
      asm volatile("s_waitcnt vmcnt(0)" ::: "memory");
    }
    __builtin_amdgcn_s_barrier();
    __builtin_amdgcn_sched_barrier(0);
    if (kt + 128 < T_SEQ) {
      const int stb = (cur == 0) ? 2 : cur - 1;  // (cur+2)%3
      STAGE(stb, kt + 128);
    }

    // ---- S^T = K Q^T: s[qf][c][r] = S[key=c*16+lhi*4+r][q=qf*16+l15] ----
    f32x4v s[2][4];
    __builtin_amdgcn_s_setprio(1);
#pragma unroll
    for (int c = 0; c < 4; ++c) {
      const int krow = c * 16 + l15;
      const half8 k0 = *(const half8*)&KhS[cur][krow * 64 + (lhi ^ sw) * 8];
      const half8 k1 =
          *(const half8*)&KhS[cur][krow * 64 + ((4 + lhi) ^ sw) * 8];
#pragma unroll
      for (int qf = 0; qf < 2; ++qf) {
        f32x4v t = (f32x4v){0.f, 0.f, 0.f, 0.f};
        t = mfma16(k0, qh[qf][0], t);
        t = mfma16(k0, ql[qf][0], t);
        t = mfma16(k1, qh[qf][1], t);
        t = mfma16(k1, ql[qf][1], t);
        s[qf][c] = t;
      }
    }
    __builtin_amdgcn_s_setprio(0);

    // V tile -> regs once (shared by both qf)
    half8 vv[4][2];
#pragma unroll
    for (int c = 0; c < 4; ++c) {
      const int vrow = c * 16 + l15;
      vv[c][0] = *(const half8*)&VtS[cur][vrow * 64 + (lhi ^ sw) * 8];
      vv[c][1] = *(const half8*)&VtS[cur][vrow * 64 + ((4 + lhi) ^ sw) * 8];
    }

    // ---- online softmax max: in-lane 16-value reduce + 2 shuffles ----
    float mx[2];
    int grow = 0;
#pragma unroll
    for (int qf = 0; qf < 2; ++qf) {
      float t0 = fmaxf(fmaxf(s[qf][0][0], s[qf][0][1]),
                       fmaxf(s[qf][0][2], s[qf][0][3]));
      float t1 = fmaxf(fmaxf(s[qf][1][0], s[qf][1][1]),
                       fmaxf(s[qf][1][2], s[qf][1][3]));
      float t2 = fmaxf(fmaxf(s[qf][2][0], s[qf][2][1]),
                       fmaxf(s[qf][2][2], s[qf][2][3]));
      float t3 = fmaxf(fmaxf(s[qf][3][0], s[qf][3][1]),
                       fmaxf(s[qf][3][2], s[qf][3][3]));
      float t = fmaxf(fmaxf(t0, t1), fmaxf(t2, t3));
      t = fmaxf(t, __shfl_xor(t, 16));
      t = fmaxf(t, __shfl_xor(t, 32));
      mx[qf] = t;
      grow |= (t > m[qf] + 8.0f) ? 1 : 0;
    }
    if (__any(grow)) {  // defer-max: rescale only on significant growth
#pragma unroll
      for (int qf = 0; qf < 2; ++qf) {
        const float mn = fmaxf(m[qf], mx[qf]);
        const float sc = __builtin_amdgcn_exp2f(m[qf] - mn);
        m[qf] = mn;
        l[qf] *= sc;
#pragma unroll
        for (int c = 0; c < 4; ++c) {
#pragma unroll
          for (int r = 0; r < 4; ++r) O[qf][c][r] *= sc;
        }
      }
    }

    // ---- per qf: P->f16->PS, psum via ones-MFMA, O^T += V^T P ----
#pragma unroll
    for (int qf = 0; qf < 2; ++qf) {
#pragma unroll
      for (int c = 0; c < 4; ++c) {
        const float p0 = __builtin_amdgcn_exp2f(s[qf][c][0] - m[qf]);
        const float p1 = __builtin_amdgcn_exp2f(s[qf][c][1] - m[qf]);
        const float p2 = __builtin_amdgcn_exp2f(s[qf][c][2] - m[qf]);
        const float p3 = __builtin_amdgcn_exp2f(s[qf][c][3] - m[qf]);
        const auto e0 = __builtin_amdgcn_cvt_pkrtz(p0, p1);  // __fp16 x2
        const auto e1 = __builtin_amdgcn_cvt_pkrtz(p2, p3);
        half4v pw;
        pw[0] = (_Float16)e0[0];
        pw[1] = (_Float16)e0[1];
        pw[2] = (_Float16)e1[0];
        pw[3] = (_Float16)e1[1];
        const int slot = (2 * c + (lhi >> 1)) ^ swz;
        *(half4v*)&PS[w][l15][slot * 8 + (lhi & 1) * 4] = pw;
      }
      const half8 pb0 = *(const half8*)&PS[w][l15][((lhi) ^ swz) * 8];
      const half8 pb1 = *(const half8*)&PS[w][l15][((lhi + 4) ^ swz) * 8];
      f32x4v ls = (f32x4v){0.f, 0.f, 0.f, 0.f};
      ls = mfma16(ones, pb0, ls);
      ls = mfma16(ones, pb1, ls);
      __builtin_amdgcn_s_setprio(1);
#pragma unroll
      for (int c = 0; c < 4; ++c) {
        O[qf][c] = mfma16(vv[c][0], pb0, O[qf][c]);
        O[qf][c] = mfma16(vv[c][1], pb1, O[qf][c]);
      }
      __builtin_amdgcn_s_setprio(0);
      l[qf] += ls[0];
    }
    cur = (cur == 2) ? 0 : cur + 1;
  }

  // ---- normalize + write merged heads as f16 hi/lo (half4 stores) ----
#pragma unroll
  for (int qf = 0; qf < 2; ++qf) {
    const float inv = 1.0f / l[qf];
    const size_t rowb =
        (size_t)(b * T_SEQ + q0 + qf * 16 + l15) * EMB + h * HD + lhi * 4;
#pragma unroll
    for (int c = 0; c < 4; ++c) {
      half4v hv, lv;
#pragma unroll
      for (int r = 0; r < 4; ++r) {
        const float v = O[qf][c][r] * inv;
        hv[r] = (_Float16)v;
        lv[r] = (_Float16)(v - (float)hv[r]);
      }
      *(half4v*)&AOh[rowb + c * 16] = hv;
      *(half4v*)&AOl[rowb + c * 16] = lv;
    }
  }
#undef STAGE
}

extern "C" void kernel_launch(void* const* d_in, const int* in_sizes, int n_in,
                              void* d_out, int out_size, void* d_ws,
                              size_t ws_size, hipStream_t stream) {
  const float* x = (const float*)d_in[0];
  const float* w_attn = (const float*)d_in[1];
  const float* b_attn = (const float*)d_in[2];
  const float* w_proj = (const float*)d_in[3];
  const float* b_proj = (const float*)d_in[4];
  float* out = (float*)d_out;

  const size_t SZX = (size_t)MROWS * EMB;  // 8388608
  const size_t SZWA = (size_t)THREE_EMB * EMB;
  const size_t SZWP = (size_t)EMB * EMB;

  _Float16* Xhi = (_Float16*)d_ws;
  _Float16* Xlo = Xhi + SZX;
  _Float16* WaHi = Xlo + SZX;
  _Float16* WaLo = WaHi + SZWA;
  _Float16* WpHi = WaLo + SZWA;
  _Float16* WpLo = WpHi + SZWP;
  _Float16* Qhi = WpLo + SZWP;
  _Float16* Qlo = Qhi + SZX;
  _Float16* Kh = Qlo + SZX;
  _Float16* Vt = Kh + SZX;  // total ~112 MiB
  // X region is dead after the QKV GEMM -> reuse for attention output
  _Float16* Ahi = Xhi;
  _Float16* Alo = Xlo;

  split_x<<<4096, 256, 0, stream>>>(x, Xhi, Xlo);
  tsplit_w<<<dim3(32, 96), 256, 0, stream>>>(w_attn, WaHi, WaLo, THREE_EMB);
  tsplit_w<<<dim3(32, 32), 256, 0, stream>>>(w_proj, WpHi, WpLo, EMB);

  mfma_gemm<0><<<dim3(64, 24), 256, 0, stream>>>(
      Xhi, Xlo, WaHi, WaLo, b_attn, nullptr, Qhi, Qlo, Kh, Vt);
  attn_kernel<<<dim3(1024), 256, 0, stream>>>(Qhi, Qlo, Kh, Vt, Ahi, Alo);
  mfma_gemm<1><<<dim3(64, 8), 256, 0, stream>>>(
      Ahi, Alo, WpHi, WpLo, b_proj, out, nullptr, nullptr, nullptr, nullptr);
}